// Round 23
// baseline (426.956 us; speedup 1.0000x reference)
//
#include <hip/hip_runtime.h>

#define NN 50000
#define EE 800000
#define GG 512
#define LL 3

typedef short bf16x8 __attribute__((ext_vector_type(8)));
typedef float f32x4  __attribute__((ext_vector_type(4)));

__device__ __forceinline__ float silu_f(float x) {
    return x * __builtin_amdgcn_rcpf(1.0f + __expf(-x));
}
__device__ __forceinline__ unsigned short bf16_rne(float x) {
    unsigned u = __float_as_uint(x);
    u += 0x7fffu + ((u >> 16) & 1u);
    return (unsigned short)(u >> 16);
}
__device__ __forceinline__ float bflo(unsigned u) { return __uint_as_float(u << 16); }
__device__ __forceinline__ float bfhi(unsigned u) { return __uint_as_float(u & 0xffff0000u); }
__device__ __forceinline__ f32x4 mfma16(bf16x8 a, bf16x8 b, f32x4 c) {
    return __builtin_amdgcn_mfma_f32_16x16x32_bf16(a, b, c, 0, 0, 0);
}
// lgkm-only barrier: drains LDS ops, leaves global loads/stores in flight.
__device__ __forceinline__ void barrier_lgkm() {
    asm volatile("s_waitcnt lgkmcnt(0)" ::: "memory");
    __builtin_amdgcn_s_barrier();
}

// ===========================================================================
// CSR build: 8-way sharded histogram -> hierarchical scan -> sharded scatter.
// ===========================================================================
__global__ __launch_bounds__(256) void hist_kernel(const int* __restrict__ ei,
                                                   int* __restrict__ deg8) {
    int e = blockIdx.x * 256 + threadIdx.x;
    if (e < EE) atomicAdd(&deg8[(e & 7) * NN + ei[EE + e]], 1);
}

__global__ __launch_bounds__(512) void scanA_kernel(const int* __restrict__ deg8,
                                                    int* __restrict__ rowptr,
                                                    int* __restrict__ bsum) {
    __shared__ int wsum[8];
    const int tid = threadIdx.x, b = blockIdx.x;
    int i = b * 512 + tid;
    int v = 0;
    if (i < NN) {
#pragma unroll
        for (int s = 0; s < 8; ++s) v += deg8[s * NN + i];
    }
    int lane = tid & 63, wid = tid >> 6;
    int x = v;
#pragma unroll
    for (int s = 1; s < 64; s <<= 1) {
        int u = __shfl_up(x, s, 64);
        if (lane >= s) x += u;
    }
    if (lane == 63) wsum[wid] = x;
    __syncthreads();
    int woff = 0;
    for (int w = 0; w < wid; ++w) woff += wsum[w];
    if (i < NN) rowptr[i] = woff + x - v;
    if (tid == 511) bsum[b] = woff + x;
}

__global__ __launch_bounds__(128) void scanB_kernel(int* __restrict__ bsum, int nb) {
    __shared__ int wsum[2];
    const int tid = threadIdx.x;
    int v = (tid < nb) ? bsum[tid] : 0;
    int lane = tid & 63, wid = tid >> 6;
    int x = v;
#pragma unroll
    for (int s = 1; s < 64; s <<= 1) {
        int u = __shfl_up(x, s, 64);
        if (lane >= s) x += u;
    }
    if (lane == 63) wsum[wid] = x;
    __syncthreads();
    int woff = (wid == 1) ? wsum[0] : 0;
    if (tid < nb) bsum[tid] = woff + x - v;
}

__global__ __launch_bounds__(512) void scanC_kernel(int* __restrict__ rowptr,
                                                    int* __restrict__ cursor8,
                                                    const int* __restrict__ deg8,
                                                    const int* __restrict__ bsum) {
    const int tid = threadIdx.x, b = blockIdx.x;
    int i = b * 512 + tid;
    if (i < NN) {
        int r = rowptr[i] + bsum[b];
        rowptr[i] = r;
        int running = r;
#pragma unroll
        for (int s = 0; s < 8; ++s) {
            cursor8[s * NN + i] = running;
            running += deg8[s * NN + i];
        }
    }
    if (i == 0) rowptr[NN] = EE;
}

__global__ __launch_bounds__(256) void scatter_kernel(const int* __restrict__ ei,
                                                      int* __restrict__ cursor8,
                                                      int2* __restrict__ epair) {
    int e = blockIdx.x * 256 + threadIdx.x;
    if (e < EE) {
        int d = ei[EE + e];
        int pos = atomicAdd(&cursor8[(e & 7) * NN + d], 1);
        epair[pos] = make_int2(ei[e], d);   // (src, dst)
    }
}

// ===========================================================================
// pk_kernel (MFMA) — round-19 proven (cols 0-63 -> Pt f32, 64-127 -> Pb bf16)
// ===========================================================================
__global__ __launch_bounds__(512, 2) void pk_kernel(
    const float* __restrict__ h, const float* __restrict__ w1g,
    float* __restrict__ Pt, unsigned short* __restrict__ Pbu, int ntiles)
{
    extern __shared__ __align__(16) char smem[];
    char*  hb = smem;                    // [128r][128B] swz : 16384
    char*  wt = hb + 16384;              // [128c][128B] swz : 16384
    float* tp = (float*)(wt + 16384);    // [128][68] f32   : 34816

    const int tid = threadIdx.x;
    const int l   = tid & 63;
    const int w   = tid >> 6;
    const int mi  = w >> 1;
    const int ni  = w & 1;
    const int l15 = l & 15;
    const int l4  = l >> 4;
    const int sw  = (l15 & 7) << 4;

    {
        int c = tid >> 2, kq0 = tid & 3;
#pragma unroll
        for (int hf = 0; hf < 2; ++hf) {
            int kq = kq0 + 4 * hf;
            const float* wp = w1g + (size_t)((c >> 6) * 64 + kq * 8) * 64 + (c & 63);
            bf16x8 bv;
#pragma unroll
            for (int j = 0; j < 8; ++j) bv[j] = (short)bf16_rne(wp[j * 64]);
            *(bf16x8*)(wt + c * 128 + ((kq * 16) ^ ((c & 7) << 4))) = bv;
        }
    }

    for (int tile = blockIdx.x; tile < ntiles; tile += gridDim.x) {
        const int base = tile * 128;
        __syncthreads();
        {
            int r = tid >> 2, q = tid & 3;
            int n = base + r;
            float v[16];
#pragma unroll
            for (int j = 0; j < 16; ++j) v[j] = 0.f;
            if (n < NN) {
                const float* hp = h + (size_t)64 * n + q * 16;
#pragma unroll
                for (int j = 0; j < 4; ++j) {
                    float4 t = *(const float4*)(hp + 4 * j);
                    v[4 * j] = t.x; v[4 * j + 1] = t.y;
                    v[4 * j + 2] = t.z; v[4 * j + 3] = t.w;
                }
            }
            bf16x8 b0, b1;
#pragma unroll
            for (int j = 0; j < 8; ++j) {
                b0[j] = (short)bf16_rne(v[j]);
                b1[j] = (short)bf16_rne(v[8 + j]);
            }
            int swr = (r & 7) << 4;
            *(bf16x8*)(hb + r * 128 + ((q * 32) ^ swr))      = b0;
            *(bf16x8*)(hb + r * 128 + ((q * 32 + 16) ^ swr)) = b1;
        }
        __syncthreads();
        f32x4 acc[2][4];
#pragma unroll
        for (int m = 0; m < 2; ++m)
#pragma unroll
            for (int n = 0; n < 4; ++n) acc[m][n] = (f32x4){0.f, 0.f, 0.f, 0.f};
#pragma unroll
        for (int ks = 0; ks < 2; ++ks) {
            int kb = ks * 64 + l4 * 16;
            bf16x8 af[2], bf[4];
#pragma unroll
            for (int m = 0; m < 2; ++m)
                af[m] = *(const bf16x8*)(hb + (32 * mi + 16 * m + l15) * 128 + (kb ^ sw));
#pragma unroll
            for (int n = 0; n < 4; ++n)
                bf[n] = *(const bf16x8*)(wt + (64 * ni + 16 * n + l15) * 128 + (kb ^ sw));
#pragma unroll
            for (int m = 0; m < 2; ++m)
#pragma unroll
                for (int n = 0; n < 4; ++n)
                    acc[m][n] = mfma16(af[m], bf[n], acc[m][n]);
        }
        __syncthreads();
        if (ni == 0) {
#pragma unroll
            for (int m = 0; m < 2; ++m)
#pragma unroll
                for (int n = 0; n < 4; ++n)
#pragma unroll
                    for (int r = 0; r < 4; ++r)
                        tp[(32 * mi + 16 * m + l4 * 4 + r) * 68 + 16 * n + l15] =
                            acc[m][n][r];
        }
        __syncthreads();
        {
            int r = tid >> 2, q = tid & 3;
            int n = base + r;
            if (n < NN) {
                float* op = Pt + (size_t)64 * n + q * 16;
#pragma unroll
                for (int j = 0; j < 4; ++j)
                    *(float4*)(op + 4 * j) = *(const float4*)&tp[r * 68 + q * 16 + 4 * j];
            }
        }
        __syncthreads();
        if (ni == 1) {
#pragma unroll
            for (int m = 0; m < 2; ++m)
#pragma unroll
                for (int n = 0; n < 4; ++n)
#pragma unroll
                    for (int r = 0; r < 4; ++r)
                        tp[(32 * mi + 16 * m + l4 * 4 + r) * 68 + 16 * n + l15] =
                            acc[m][n][r];
        }
        __syncthreads();
        {
            int r = tid >> 2, q = tid & 3;
            int n = base + r;
            if (n < NN) {
                unsigned uu[8];
#pragma unroll
                for (int j = 0; j < 8; ++j) {
                    float lo = tp[r * 68 + q * 16 + 2 * j];
                    float hi = tp[r * 68 + q * 16 + 2 * j + 1];
                    uu[j] = ((unsigned)bf16_rne(hi) << 16) | bf16_rne(lo);
                }
                uint4* op = (uint4*)(Pbu + (size_t)64 * n + q * 16);
                op[0] = make_uint4(uu[0], uu[1], uu[2], uu[3]);
                op[1] = make_uint4(uu[4], uu[5], uu[6], uu[7]);
            }
        }
    }
}

// ===========================================================================
// Edge kernel — round-14/17 structure; packed int2 IDX. UNCHANGED.
// ===========================================================================
__global__ __launch_bounds__(512, 6) void edge_kernel(
    const float* __restrict__ Pt, const unsigned short* __restrict__ Pbu,
    const int2* __restrict__ epair,
    const float* __restrict__ b1g,
    const float* __restrict__ w2g, const float* __restrict__ b2g,
    unsigned short* __restrict__ m2g, int ntiles)
{
    extern __shared__ __align__(16) char smem[];
    char*  wt2s = smem;                       // [64c][128B] swz   8192
    char*  m1s  = wt2s + 8192;                // [128r][128B] swz 16384
    float* b1s  = (float*)(m1s + 16384);      // 64 f32
    float* b2s  = b1s + 64;                   // 64 f32

    const int tid = threadIdx.x;
    const int l   = tid & 63;
    const int w   = tid >> 6;
    const int mi  = w >> 1;
    const int ni  = w & 1;
    const int l15 = l & 15;
    const int l4  = l >> 4;
    const int g7  = tid & 7;

    {
        int c = tid >> 3, kc = tid & 7;
        const float* wp = w2g + (kc * 8) * 64 + c;
        bf16x8 bv;
#pragma unroll
        for (int j = 0; j < 8; ++j) bv[j] = (short)bf16_rne(wp[j * 64]);
        *(bf16x8*)(wt2s + c * 128 + ((kc * 16) ^ ((c & 7) << 4))) = bv;
    }
    if (tid < 64) { b1s[tid] = b1g[tid]; b2s[tid] = b2g[tid]; }

    int    ix_d[2], ix_s[2];
    float4 pf_a0[2], pf_a1[2];
    uint4  pf_pb[2];

    auto IDX = [&](int tt) {
        int eb = tt * 128;
#pragma unroll
        for (int it = 0; it < 2; ++it) {
            int e = (it * 512 + tid) >> 3;
            int2 p = epair[eb + e];
            ix_s[it] = p.x;
            ix_d[it] = p.y;
        }
    };
    auto DATA = [&]() {
#pragma unroll
        for (int it = 0; it < 2; ++it) {
            const float* pt = Pt + (size_t)64 * ix_d[it] + 8 * g7;
            pf_a0[it] = *(const float4*)pt;
            pf_a1[it] = *(const float4*)(pt + 4);
            pf_pb[it] = *(const uint4*)(Pbu + (size_t)64 * ix_s[it] + 8 * g7);
        }
    };

    int tile = blockIdx.x;
    if (tile < ntiles) { IDX(tile); DATA(); }
    if (tile + gridDim.x < ntiles) IDX(tile + gridDim.x);
    barrier_lgkm();

    for (; tile < ntiles; tile += gridDim.x) {
#pragma unroll
        for (int it = 0; it < 2; ++it) {
            int e = (it * 512 + tid) >> 3;
            float4 b0  = *(const float4*)(b1s + 8 * g7);
            float4 b1v = *(const float4*)(b1s + 8 * g7 + 4);
            float v0 = silu_f(pf_a0[it].x + bflo(pf_pb[it].x) + b0.x);
            float v1 = silu_f(pf_a0[it].y + bfhi(pf_pb[it].x) + b0.y);
            float v2 = silu_f(pf_a0[it].z + bflo(pf_pb[it].y) + b0.z);
            float v3 = silu_f(pf_a0[it].w + bfhi(pf_pb[it].y) + b0.w);
            float v4 = silu_f(pf_a1[it].x + bflo(pf_pb[it].z) + b1v.x);
            float v5 = silu_f(pf_a1[it].y + bfhi(pf_pb[it].z) + b1v.y);
            float v6 = silu_f(pf_a1[it].z + bflo(pf_pb[it].w) + b1v.z);
            float v7 = silu_f(pf_a1[it].w + bfhi(pf_pb[it].w) + b1v.w);
            uint4 o;
            o.x = ((unsigned)bf16_rne(v1) << 16) | bf16_rne(v0);
            o.y = ((unsigned)bf16_rne(v3) << 16) | bf16_rne(v2);
            o.z = ((unsigned)bf16_rne(v5) << 16) | bf16_rne(v4);
            o.w = ((unsigned)bf16_rne(v7) << 16) | bf16_rne(v6);
            *(uint4*)(m1s + e * 128 + ((g7 * 16) ^ ((e & 7) << 4))) = o;
        }
        barrier_lgkm();                           // B1: m1s ready
        int nxt = tile + gridDim.x;
        if (nxt < ntiles) {
            DATA();
            if (nxt + gridDim.x < ntiles) IDX(nxt + gridDim.x);
        }
        f32x4 acc2[2][2];
#pragma unroll
        for (int m = 0; m < 2; ++m)
#pragma unroll
            for (int n = 0; n < 2; ++n) {
                float b = b2s[32 * ni + 16 * n + l15];
                acc2[m][n] = (f32x4){b, b, b, b};
            }
        const int sw = (l15 & 7) << 4;
#pragma unroll
        for (int ks = 0; ks < 2; ++ks) {
            int kb = ks * 64 + l4 * 16;
            bf16x8 af[2], bfr[2];
#pragma unroll
            for (int m = 0; m < 2; ++m)
                af[m] = *(const bf16x8*)(m1s + (32 * mi + 16 * m + l15) * 128 + (kb ^ sw));
#pragma unroll
            for (int n = 0; n < 2; ++n)
                bfr[n] = *(const bf16x8*)(wt2s + (32 * ni + 16 * n + l15) * 128 + (kb ^ sw));
#pragma unroll
            for (int m = 0; m < 2; ++m)
#pragma unroll
                for (int n = 0; n < 2; ++n)
                    acc2[m][n] = mfma16(af[m], bfr[n], acc2[m][n]);
        }
        unsigned short* mg = m2g + (size_t)(tile * 128) * 64;
#pragma unroll
        for (int m = 0; m < 2; ++m)
#pragma unroll
            for (int n = 0; n < 2; ++n)
#pragma unroll
                for (int r = 0; r < 4; ++r) {
                    int row = 32 * mi + 16 * m + l4 * 4 + r;
                    int col = 32 * ni + 16 * n + l15;
                    mg[row * 64 + col] = bf16_rne(silu_f(acc2[m][n][r]));
                }
        barrier_lgkm();                           // B2
    }
}

// ===========================================================================
// agg_kernel v2: thread = (node, 8-col group); uint4 (16B) loads, 4-deep
// unroll, 8 f32 accumulators; two coalesced float4 stores. Read-side only.
// ===========================================================================
__global__ __launch_bounds__(256) void agg_kernel(
    const unsigned short* __restrict__ m2g, const int* __restrict__ rowptr,
    float* __restrict__ agg)
{
    int idx = blockIdx.x * 256 + threadIdx.x;
    if (idx >= NN * 8) return;
    int n = idx >> 3, c = idx & 7;            // c: 8-bf16 (16B) column group
    int e0 = rowptr[n], e1 = rowptr[n + 1];
    float a[8];
#pragma unroll
    for (int j = 0; j < 8; ++j) a[j] = 0.f;
    int e = e0;
    for (; e + 4 <= e1; e += 4) {
        uint4 u0 = *(const uint4*)(m2g + (size_t)(e + 0) * 64 + 8 * c);
        uint4 u1 = *(const uint4*)(m2g + (size_t)(e + 1) * 64 + 8 * c);
        uint4 u2 = *(const uint4*)(m2g + (size_t)(e + 2) * 64 + 8 * c);
        uint4 u3 = *(const uint4*)(m2g + (size_t)(e + 3) * 64 + 8 * c);
        a[0] += (bflo(u0.x) + bflo(u1.x)) + (bflo(u2.x) + bflo(u3.x));
        a[1] += (bfhi(u0.x) + bfhi(u1.x)) + (bfhi(u2.x) + bfhi(u3.x));
        a[2] += (bflo(u0.y) + bflo(u1.y)) + (bflo(u2.y) + bflo(u3.y));
        a[3] += (bfhi(u0.y) + bfhi(u1.y)) + (bfhi(u2.y) + bfhi(u3.y));
        a[4] += (bflo(u0.z) + bflo(u1.z)) + (bflo(u2.z) + bflo(u3.z));
        a[5] += (bfhi(u0.z) + bfhi(u1.z)) + (bfhi(u2.z) + bfhi(u3.z));
        a[6] += (bflo(u0.w) + bflo(u1.w)) + (bflo(u2.w) + bflo(u3.w));
        a[7] += (bfhi(u0.w) + bfhi(u1.w)) + (bfhi(u2.w) + bfhi(u3.w));
    }
    for (; e < e1; ++e) {
        uint4 u = *(const uint4*)(m2g + (size_t)e * 64 + 8 * c);
        a[0] += bflo(u.x); a[1] += bfhi(u.x);
        a[2] += bflo(u.y); a[3] += bfhi(u.y);
        a[4] += bflo(u.z); a[5] += bfhi(u.z);
        a[6] += bflo(u.w); a[7] += bfhi(u.w);
    }
    float* ap = agg + (size_t)64 * n + 8 * c;
    *(float4*)(ap + 0) = make_float4(a[0], a[1], a[2], a[3]);
    *(float4*)(ap + 4) = make_float4(a[4], a[5], a[6], a[7]);
}

// ===========================================================================
// node_mfma_kernel — round-22 proven. UNCHANGED.
// ===========================================================================
__global__ __launch_bounds__(512, 1) void node_mfma_kernel(
    const float* __restrict__ h, const float* __restrict__ agg,
    const float* __restrict__ w1g, const float* __restrict__ b1g,
    const float* __restrict__ w2g, const float* __restrict__ b2g,
    float* __restrict__ outp, int ntiles)
{
    extern __shared__ __align__(16) char smem[];
    char*  hbA = smem;                    // 16384 (k 0-63 = h)
    char*  hbB = hbA + 16384;             // 16384 (k 64-127 = agg)
    char*  wtA = hbB + 16384;             //  8192 (W1 k 0-63)
    char*  wtB = wtA + 8192;              //  8192 (W1 k 64-127)
    char*  wt2 = wtB + 8192;              //  8192 (W2)
    char*  m1s = wt2 + 8192;              // 16384 (bf16 m1)
    float* tp  = (float*)(m1s + 16384);   // 34816
    float* b1s = (float*)((char*)tp + 34816);  // 64
    float* b2s = b1s + 64;                     // 64

    const int tid = threadIdx.x;
    const int l   = tid & 63;
    const int w   = tid >> 6;
    const int mi  = w >> 1;
    const int ni  = w & 1;
    const int l15 = l & 15;
    const int l4  = l >> 4;
    const int sw  = (l15 & 7) << 4;

    {
        int c = tid >> 3, kc = tid & 7;
        const float* wpA = w1g + (kc * 8) * 64 + c;
        const float* wpB = w1g + (64 + kc * 8) * 64 + c;
        const float* wp2 = w2g + (kc * 8) * 64 + c;
        bf16x8 bA, bB, b2v;
#pragma unroll
        for (int j = 0; j < 8; ++j) {
            bA[j]  = (short)bf16_rne(wpA[j * 64]);
            bB[j]  = (short)bf16_rne(wpB[j * 64]);
            b2v[j] = (short)bf16_rne(wp2[j * 64]);
        }
        int off = c * 128 + ((kc * 16) ^ ((c & 7) << 4));
        *(bf16x8*)(wtA + off) = bA;
        *(bf16x8*)(wtB + off) = bB;
        *(bf16x8*)(wt2 + off) = b2v;
    }
    if (tid < 64) { b1s[tid] = b1g[tid]; b2s[tid] = b2g[tid]; }

    for (int tile = blockIdx.x; tile < ntiles; tile += gridDim.x) {
        const int base = tile * 128;
        __syncthreads();
        {
            int r = tid >> 2, q = tid & 3;
            int n = base + r;
            int swr = (r & 7) << 4;
#pragma unroll
            for (int srcsel = 0; srcsel < 2; ++srcsel) {
                const float* src = srcsel ? agg : h;
                char* dst = srcsel ? hbB : hbA;
                float v[16];
#pragma unroll
                for (int j = 0; j < 16; ++j) v[j] = 0.f;
                if (n < NN) {
                    const float* hp = src + (size_t)64 * n + q * 16;
#pragma unroll
                    for (int j = 0; j < 4; ++j) {
                        float4 t = *(const float4*)(hp + 4 * j);
                        v[4 * j] = t.x; v[4 * j + 1] = t.y;
                        v[4 * j + 2] = t.z; v[4 * j + 3] = t.w;
                    }
                }
                bf16x8 c0, c1;
#pragma unroll
                for (int j = 0; j < 8; ++j) {
                    c0[j] = (short)bf16_rne(v[j]);
                    c1[j] = (short)bf16_rne(v[8 + j]);
                }
                *(bf16x8*)(dst + r * 128 + ((q * 32) ^ swr))      = c0;
                *(bf16x8*)(dst + r * 128 + ((q * 32 + 16) ^ swr)) = c1;
            }
        }
        __syncthreads();
        f32x4 acc[2][2];
#pragma unroll
        for (int m = 0; m < 2; ++m)
#pragma unroll
            for (int n = 0; n < 2; ++n) {
                float b = b1s[32 * ni + 16 * n + l15];
                acc[m][n] = (f32x4){b, b, b, b};
            }
#pragma unroll
        for (int half = 0; half < 2; ++half) {
            const char* hb = half ? hbB : hbA;
            const char* wt = half ? wtB : wtA;
#pragma unroll
            for (int ks = 0; ks < 2; ++ks) {
                int kb = ks * 64 + l4 * 16;
                bf16x8 af[2], bf[2];
#pragma unroll
                for (int m = 0; m < 2; ++m)
                    af[m] = *(const bf16x8*)(hb + (32 * mi + 16 * m + l15) * 128 + (kb ^ sw));
#pragma unroll
                for (int n = 0; n < 2; ++n)
                    bf[n] = *(const bf16x8*)(wt + (32 * ni + 16 * n + l15) * 128 + (kb ^ sw));
#pragma unroll
                for (int m = 0; m < 2; ++m)
#pragma unroll
                    for (int n = 0; n < 2; ++n)
                        acc[m][n] = mfma16(af[m], bf[n], acc[m][n]);
            }
        }
#pragma unroll
        for (int m = 0; m < 2; ++m)
#pragma unroll
            for (int n = 0; n < 2; ++n)
#pragma unroll
                for (int r = 0; r < 4; ++r) {
                    int row = 32 * mi + 16 * m + l4 * 4 + r;
                    int col = 32 * ni + 16 * n + l15;
                    *(unsigned short*)(m1s + row * 128 + ((col * 2) ^ ((row & 7) << 4))) =
                        bf16_rne(silu_f(acc[m][n][r]));
                }
        __syncthreads();
        f32x4 acc2[2][2];
#pragma unroll
        for (int m = 0; m < 2; ++m)
#pragma unroll
            for (int n = 0; n < 2; ++n) {
                float b = b2s[32 * ni + 16 * n + l15];
                acc2[m][n] = (f32x4){b, b, b, b};
            }
#pragma unroll
        for (int ks = 0; ks < 2; ++ks) {
            int kb = ks * 64 + l4 * 16;
            bf16x8 af[2], bfr[2];
#pragma unroll
            for (int m = 0; m < 2; ++m)
                af[m] = *(const bf16x8*)(m1s + (32 * mi + 16 * m + l15) * 128 + (kb ^ sw));
#pragma unroll
            for (int n = 0; n < 2; ++n)
                bfr[n] = *(const bf16x8*)(wt2 + (32 * ni + 16 * n + l15) * 128 + (kb ^ sw));
#pragma unroll
            for (int m = 0; m < 2; ++m)
#pragma unroll
                for (int n = 0; n < 2; ++n)
                    acc2[m][n] = mfma16(af[m], bfr[n], acc2[m][n]);
        }
#pragma unroll
        for (int m = 0; m < 2; ++m)
#pragma unroll
            for (int n = 0; n < 2; ++n)
#pragma unroll
                for (int r = 0; r < 4; ++r)
                    tp[(32 * mi + 16 * m + l4 * 4 + r) * 68 + 32 * ni + 16 * n + l15] =
                        acc2[m][n][r];
        __syncthreads();
        {
            int r = tid >> 2, q = tid & 3;
            int n = base + r;
            if (n < NN) {
                const float* hp = h + (size_t)64 * n + q * 16;
                float* op = outp + (size_t)64 * n + q * 16;
#pragma unroll
                for (int j = 0; j < 4; ++j) {
                    float4 hv = *(const float4*)(hp + 4 * j);
                    const float* tv = &tp[r * 68 + q * 16 + 4 * j];
                    *(float4*)(op + 4 * j) = make_float4(
                        tv[0] + hv.x, tv[1] + hv.y, tv[2] + hv.z, tv[3] + hv.w);
                }
            }
        }
    }
}

// ===========================================================================
// Readout row-MLP (K1=64, segmented scatter into gsum) — unchanged.
// ===========================================================================
__global__ __launch_bounds__(512, 1) void rowmlp_ro_kernel(
    const float* __restrict__ A,
    const float* __restrict__ w1g, const float* __restrict__ b1g,
    const float* __restrict__ w2g, const float* __restrict__ b2g,
    const int* __restrict__ seg, float* __restrict__ outp,
    int nrows, int ntiles)
{
    extern __shared__ float lds[];
    float* ws1  = lds;
    float* ws2  = ws1 + 4096;
    float* wb1  = ws2 + 4096;
    float* wb2  = wb1 + 64;
    float* cats = wb2 + 64;
    float* m1s  = cats + 128 * 68;
    int*   segs = (int*)(m1s + 128 * 68);

    const int tid = threadIdx.x;
    const int tr  = tid & 31;
    const int tc  = tid >> 5;

    for (int i = tid; i < 1024; i += 512) {
        *(float4*)&ws1[4 * i] = *(const float4*)&w1g[4 * i];
        *(float4*)&ws2[4 * i] = *(const float4*)&w2g[4 * i];
    }
    if (tid < 64) { wb1[tid] = b1g[tid]; wb2[tid] = b2g[tid]; }

    for (int tile = blockIdx.x; tile < ntiles; tile += gridDim.x) {
        const int base = tile * 128;
        __syncthreads();
        if (tid < 128) segs[tid] = (base + tid < nrows) ? seg[base + tid] : -1;
#pragma unroll
        for (int rep = 0; rep < 4; ++rep) {
            int idx = rep * 512 + tid;
            int r = idx >> 4, q = idx & 15;
            int n = base + r;
            float4 v = make_float4(0.f, 0.f, 0.f, 0.f);
            if (n < nrows) v = *(const float4*)(A + 64 * n + 4 * q);
            *(float4*)&cats[r * 68 + 4 * q] = v;
        }
        __syncthreads();
        float acc[4][4];
#pragma unroll
        for (int jj = 0; jj < 4; ++jj)
#pragma unroll
            for (int ii = 0; ii < 4; ++ii) acc[jj][ii] = wb1[4 * tc + ii];
#pragma unroll 4
        for (int k16 = 0; k16 < 16; ++k16) {
            float4 bv0 = *(const float4*)&ws1[(4 * k16 + 0) * 64 + 4 * tc];
            float4 bv1 = *(const float4*)&ws1[(4 * k16 + 1) * 64 + 4 * tc];
            float4 bv2 = *(const float4*)&ws1[(4 * k16 + 2) * 64 + 4 * tc];
            float4 bv3 = *(const float4*)&ws1[(4 * k16 + 3) * 64 + 4 * tc];
#pragma unroll
            for (int jj = 0; jj < 4; ++jj) {
                float4 av = *(const float4*)&cats[(tr + 32 * jj) * 68 + 4 * k16];
                acc[jj][0] = fmaf(av.x, bv0.x, fmaf(av.y, bv1.x, fmaf(av.z, bv2.x, fmaf(av.w, bv3.x, acc[jj][0]))));
                acc[jj][1] = fmaf(av.x, bv0.y, fmaf(av.y, bv1.y, fmaf(av.z, bv2.y, fmaf(av.w, bv3.y, acc[jj][1]))));
                acc[jj][2] = fmaf(av.x, bv0.z, fmaf(av.y, bv1.z, fmaf(av.z, bv2.z, fmaf(av.w, bv3.z, acc[jj][2]))));
                acc[jj][3] = fmaf(av.x, bv0.w, fmaf(av.y, bv1.w, fmaf(av.z, bv2.w, fmaf(av.w, bv3.w, acc[jj][3]))));
            }
        }
#pragma unroll
        for (int jj = 0; jj < 4; ++jj) {
            float4 v;
            v.x = silu_f(acc[jj][0]); v.y = silu_f(acc[jj][1]);
            v.z = silu_f(acc[jj][2]); v.w = silu_f(acc[jj][3]);
            *(float4*)&m1s[(tr + 32 * jj) * 68 + 4 * tc] = v;
        }
        __syncthreads();
        float acc2[4][4];
#pragma unroll
        for (int jj = 0; jj < 4; ++jj)
#pragma unroll
            for (int ii = 0; ii < 4; ++ii) acc2[jj][ii] = wb2[4 * tc + ii];
#pragma unroll 4
        for (int k16 = 0; k16 < 16; ++k16) {
            float4 bv0 = *(const float4*)&ws2[(4 * k16 + 0) * 64 + 4 * tc];
            float4 bv1 = *(const float4*)&ws2[(4 * k16 + 1) * 64 + 4 * tc];
            float4 bv2 = *(const float4*)&ws2[(4 * k16 + 2) * 64 + 4 * tc];
            float4 bv3 = *(const float4*)&ws2[(4 * k16 + 3) * 64 + 4 * tc];
#pragma unroll
            for (int jj = 0; jj < 4; ++jj) {
                float4 av = *(const float4*)&m1s[(tr + 32 * jj) * 68 + 4 * k16];
                acc2[jj][0] = fmaf(av.x, bv0.x, fmaf(av.y, bv1.x, fmaf(av.z, bv2.x, fmaf(av.w, bv3.x, acc2[jj][0]))));
                acc2[jj][1] = fmaf(av.x, bv0.y, fmaf(av.y, bv1.y, fmaf(av.z, bv2.y, fmaf(av.w, bv3.y, acc2[jj][1]))));
                acc2[jj][2] = fmaf(av.x, bv0.z, fmaf(av.y, bv1.z, fmaf(av.z, bv2.z, fmaf(av.w, bv3.z, acc2[jj][2]))));
                acc2[jj][3] = fmaf(av.x, bv0.w, fmaf(av.y, bv1.w, fmaf(av.z, bv2.w, fmaf(av.w, bv3.w, acc2[jj][3]))));
            }
        }
#pragma unroll
        for (int jj = 0; jj < 4; ++jj) {
            int r = tr + 32 * jj;
            int n = base + r;
            int gid = segs[r];
            float4 vv = (n < nrows) ? make_float4(acc2[jj][0], acc2[jj][1], acc2[jj][2], acc2[jj][3])
                                    : make_float4(0.f, 0.f, 0.f, 0.f);
            unsigned f = (tr == 0 || segs[(r > 0) ? r - 1 : 0] != gid) ? 1u : 0u;
#pragma unroll
            for (int s = 1; s < 32; s <<= 1) {
                float ux = __shfl_up(vv.x, s, 32);
                float uy = __shfl_up(vv.y, s, 32);
                float uz = __shfl_up(vv.z, s, 32);
                float uw = __shfl_up(vv.w, s, 32);
                unsigned uf = __shfl_up(f, s, 32);
                if (tr >= s) {
                    if (!f) { vv.x += ux; vv.y += uy; vv.z += uz; vv.w += uw; }
                    f |= uf;
                }
            }
            bool tail = (tr == 31) || (segs[r + 1] != gid);
            if (tail && gid >= 0) {
                float* bp = outp + 64 * gid + 4 * tc;
                atomicAdd(bp + 0, vv.x); atomicAdd(bp + 1, vv.y);
                atomicAdd(bp + 2, vv.z); atomicAdd(bp + 3, vv.w);
            }
        }
    }
}

__global__ __launch_bounds__(256) void proj_kernel(
    const float* __restrict__ x, const float* __restrict__ w,
    const float* __restrict__ b, float* __restrict__ h, int n)
{
    int i = blockIdx.x * 256 + threadIdx.x;
    if (i >= n * 64) return;
    int node = i >> 6, j = i & 63;
    const float* xr = x + node * 14;
    float acc = b[j];
#pragma unroll
    for (int k = 0; k < 14; ++k) acc = fmaf(xr[k], w[k * 64 + j], acc);
    h[i] = acc;
}

__global__ __launch_bounds__(256) void head_kernel(
    const float* __restrict__ gsum,
    const float* __restrict__ w3, const float* __restrict__ b3,
    const float* __restrict__ w4, const float* __restrict__ b4,
    float* __restrict__ out, int g_count)
{
    int wid  = (blockIdx.x * 256 + threadIdx.x) >> 6;
    int lane = threadIdx.x & 63;
    if (wid >= g_count) return;
    float v = gsum[wid * 64 + lane];
    float t = b3[lane];
#pragma unroll
    for (int k = 0; k < 64; ++k) {
        float a = __shfl(v, k, 64);
        t = fmaf(a, w3[k * 64 + lane], t);
    }
    t = silu_f(t);
    float r = t * w4[lane];
#pragma unroll
    for (int off = 32; off; off >>= 1) r += __shfl_down(r, off, 64);
    if (lane == 0) out[wid] = r + b4[0];
}

extern "C" void kernel_launch(void* const* d_in, const int* in_sizes, int n_in,
                              void* d_out, int out_size, void* d_ws, size_t ws_size,
                              hipStream_t stream)
{
    const float* x      = (const float*)d_in[0];
    const int*   ei     = (const int*)d_in[2];
    const int*   batch  = (const int*)d_in[3];
    const float* proj_w = (const float*)d_in[4];
    const float* proj_b = (const float*)d_in[5];
    const float* ew1 = (const float*)d_in[6];
    const float* eb1 = (const float*)d_in[7];
    const float* ew2 = (const float*)d_in[8];
    const float* eb2 = (const float*)d_in[9];
    const float* nw1 = (const float*)d_in[10];
    const float* nb1 = (const float*)d_in[11];
    const float* nw2 = (const float*)d_in[12];
    const float* nb2 = (const float*)d_in[13];
    const float* l1w = (const float*)d_in[14]; const float* l1b = (const float*)d_in[15];
    const float* l2w = (const float*)d_in[16]; const float* l2b = (const float*)d_in[17];
    const float* l3w = (const float*)d_in[18]; const float* l3b = (const float*)d_in[19];
    const float* l4w = (const float*)d_in[20]; const float* l4b = (const float*)d_in[21];

    float* out  = (float*)d_out;
    float* h    = out + GG;                      // per_atom_out doubles as h

    unsigned short* m2g = (unsigned short*)d_ws;             // [E,64] bf16 = 102.4MB
    float* gsum = (float*)(m2g + (size_t)EE * 64);           // [G,64]
    float* Pt   = gsum + (size_t)GG * 64;                    // [N,64] f32
    unsigned short* Pbu = (unsigned short*)(Pt + (size_t)NN * 64);  // [N,64] bf16
    int* deg8    = (int*)(Pbu + (size_t)NN * 64);            // [8][N]
    int* rowptr  = deg8 + 8 * NN;                            // N+1
    int* cursor8 = rowptr + NN + 1;                          // [8][N]
    int2* epair  = (int2*)(((uintptr_t)(cursor8 + 8 * NN) + 15) & ~(uintptr_t)15);  // [E]
    int* bsum    = (int*)(epair + EE);                       // [98]
    float* agg   = Pt;  // alias: Pt dead after edge_kernel, rebuilt next layer

    const size_t edge_lds = 8192 + 16384 + 256 + 256;                 // 25088
    const size_t pk_lds   = 16384 + 16384 + 34816;                    // 67584
    const size_t node_lds = 16384 * 3 + 8192 * 3 + 34816 + 512;       // 109056
    const size_t ro_lds   = (size_t)(4096 + 4096 + 128 + 128 * 68 + 128 * 68) * 4 + 128 * 4;

    (void)hipFuncSetAttribute((const void*)edge_kernel,
                              hipFuncAttributeMaxDynamicSharedMemorySize, (int)edge_lds);
    (void)hipFuncSetAttribute((const void*)pk_kernel,
                              hipFuncAttributeMaxDynamicSharedMemorySize, (int)pk_lds);
    (void)hipFuncSetAttribute((const void*)node_mfma_kernel,
                              hipFuncAttributeMaxDynamicSharedMemorySize, (int)node_lds);
    (void)hipFuncSetAttribute((const void*)rowmlp_ro_kernel,
                              hipFuncAttributeMaxDynamicSharedMemorySize, (int)ro_lds);

    // --- CSR build (8-way sharded, dst-sorted packed edge list) ---
    const int nb = (NN + 511) / 512;           // 98
    hipMemsetAsync(deg8, 0, (size_t)8 * NN * sizeof(int), stream);
    hipMemsetAsync(gsum, 0, (size_t)GG * 64 * sizeof(float), stream);
    hist_kernel<<<(EE + 255) / 256, 256, 0, stream>>>(ei, deg8);
    scanA_kernel<<<nb, 512, 0, stream>>>(deg8, rowptr, bsum);
    scanB_kernel<<<1, 128, 0, stream>>>(bsum, nb);
    scanC_kernel<<<nb, 512, 0, stream>>>(rowptr, cursor8, deg8, bsum);
    scatter_kernel<<<(EE + 255) / 256, 256, 0, stream>>>(ei, cursor8, epair);

    proj_kernel<<<(NN * 64 + 255) / 256, 256, 0, stream>>>(x, proj_w, proj_b, h, NN);

    const int etiles = EE / 128;               // 6250 (exact)
    const int ntiles = (NN + 127) / 128;       // 391
    for (int l = 0; l < LL; ++l) {
        pk_kernel<<<ntiles, 512, pk_lds, stream>>>(h, ew1 + l * 8192, Pt, Pbu, ntiles);
        edge_kernel<<<1024, 512, edge_lds, stream>>>(
            Pt, Pbu, epair, eb1 + l * 64, ew2 + l * 4096, eb2 + l * 64,
            m2g, etiles);
        agg_kernel<<<(NN * 8 + 255) / 256, 256, 0, stream>>>(m2g, rowptr, agg);
        node_mfma_kernel<<<196, 512, node_lds, stream>>>(
            h, agg, nw1 + l * 8192, nb1 + l * 64, nw2 + l * 4096, nb2 + l * 64,
            h, ntiles);
    }
    rowmlp_ro_kernel<<<196, 512, ro_lds, stream>>>(
        h, l1w, l1b, l2w, l2b, batch, gsum, NN, ntiles);
    head_kernel<<<GG / 4, 256, 0, stream>>>(gsum, l3w, l3b, l4w, l4b, out, GG);
}

// Round 24
// 424.336 us; speedup vs baseline: 1.0062x; 1.0062x over previous
//
#include <hip/hip_runtime.h>

#define NN 50000
#define EE 800000
#define GG 512
#define LL 3

typedef short bf16x8 __attribute__((ext_vector_type(8)));
typedef float f32x4  __attribute__((ext_vector_type(4)));

__device__ __forceinline__ float silu_f(float x) {
    return x * __builtin_amdgcn_rcpf(1.0f + __expf(-x));
}
__device__ __forceinline__ unsigned short bf16_rne(float x) {
    unsigned u = __float_as_uint(x);
    u += 0x7fffu + ((u >> 16) & 1u);
    return (unsigned short)(u >> 16);
}
__device__ __forceinline__ float bflo(unsigned u) { return __uint_as_float(u << 16); }
__device__ __forceinline__ float bfhi(unsigned u) { return __uint_as_float(u & 0xffff0000u); }
__device__ __forceinline__ f32x4 mfma16(bf16x8 a, bf16x8 b, f32x4 c) {
    return __builtin_amdgcn_mfma_f32_16x16x32_bf16(a, b, c, 0, 0, 0);
}
// lgkm-only barrier: drains LDS ops, leaves global loads/stores in flight.
__device__ __forceinline__ void barrier_lgkm() {
    asm volatile("s_waitcnt lgkmcnt(0)" ::: "memory");
    __builtin_amdgcn_s_barrier();
}

// ===========================================================================
// CSR build: 8-way sharded histogram -> hierarchical scan -> sharded scatter.
// ===========================================================================
__global__ __launch_bounds__(256) void hist_kernel(const int* __restrict__ ei,
                                                   int* __restrict__ deg8) {
    int e = blockIdx.x * 256 + threadIdx.x;
    if (e < EE) atomicAdd(&deg8[(e & 7) * NN + ei[EE + e]], 1);
}

__global__ __launch_bounds__(512) void scanA_kernel(const int* __restrict__ deg8,
                                                    int* __restrict__ rowptr,
                                                    int* __restrict__ bsum) {
    __shared__ int wsum[8];
    const int tid = threadIdx.x, b = blockIdx.x;
    int i = b * 512 + tid;
    int v = 0;
    if (i < NN) {
#pragma unroll
        for (int s = 0; s < 8; ++s) v += deg8[s * NN + i];
    }
    int lane = tid & 63, wid = tid >> 6;
    int x = v;
#pragma unroll
    for (int s = 1; s < 64; s <<= 1) {
        int u = __shfl_up(x, s, 64);
        if (lane >= s) x += u;
    }
    if (lane == 63) wsum[wid] = x;
    __syncthreads();
    int woff = 0;
    for (int w = 0; w < wid; ++w) woff += wsum[w];
    if (i < NN) rowptr[i] = woff + x - v;
    if (tid == 511) bsum[b] = woff + x;
}

__global__ __launch_bounds__(128) void scanB_kernel(int* __restrict__ bsum, int nb) {
    __shared__ int wsum[2];
    const int tid = threadIdx.x;
    int v = (tid < nb) ? bsum[tid] : 0;
    int lane = tid & 63, wid = tid >> 6;
    int x = v;
#pragma unroll
    for (int s = 1; s < 64; s <<= 1) {
        int u = __shfl_up(x, s, 64);
        if (lane >= s) x += u;
    }
    if (lane == 63) wsum[wid] = x;
    __syncthreads();
    int woff = (wid == 1) ? wsum[0] : 0;
    if (tid < nb) bsum[tid] = woff + x - v;
}

__global__ __launch_bounds__(512) void scanC_kernel(int* __restrict__ rowptr,
                                                    int* __restrict__ cursor8,
                                                    const int* __restrict__ deg8,
                                                    const int* __restrict__ bsum) {
    const int tid = threadIdx.x, b = blockIdx.x;
    int i = b * 512 + tid;
    if (i < NN) {
        int r = rowptr[i] + bsum[b];
        rowptr[i] = r;
        int running = r;
#pragma unroll
        for (int s = 0; s < 8; ++s) {
            cursor8[s * NN + i] = running;
            running += deg8[s * NN + i];
        }
    }
    if (i == 0) rowptr[NN] = EE;
}

__global__ __launch_bounds__(256) void scatter_kernel(const int* __restrict__ ei,
                                                      int* __restrict__ cursor8,
                                                      int2* __restrict__ epair) {
    int e = blockIdx.x * 256 + threadIdx.x;
    if (e < EE) {
        int d = ei[EE + e];
        int pos = atomicAdd(&cursor8[(e & 7) * NN + d], 1);
        epair[pos] = make_int2(ei[e], d);   // (src, dst)
    }
}

// ===========================================================================
// pk_kernel (MFMA) — round-19 proven (cols 0-63 -> Pt f32, 64-127 -> Pb bf16)
// ===========================================================================
__global__ __launch_bounds__(512, 2) void pk_kernel(
    const float* __restrict__ h, const float* __restrict__ w1g,
    float* __restrict__ Pt, unsigned short* __restrict__ Pbu, int ntiles)
{
    extern __shared__ __align__(16) char smem[];
    char*  hb = smem;                    // [128r][128B] swz : 16384
    char*  wt = hb + 16384;              // [128c][128B] swz : 16384
    float* tp = (float*)(wt + 16384);    // [128][68] f32   : 34816

    const int tid = threadIdx.x;
    const int l   = tid & 63;
    const int w   = tid >> 6;
    const int mi  = w >> 1;
    const int ni  = w & 1;
    const int l15 = l & 15;
    const int l4  = l >> 4;
    const int sw  = (l15 & 7) << 4;

    {
        int c = tid >> 2, kq0 = tid & 3;
#pragma unroll
        for (int hf = 0; hf < 2; ++hf) {
            int kq = kq0 + 4 * hf;
            const float* wp = w1g + (size_t)((c >> 6) * 64 + kq * 8) * 64 + (c & 63);
            bf16x8 bv;
#pragma unroll
            for (int j = 0; j < 8; ++j) bv[j] = (short)bf16_rne(wp[j * 64]);
            *(bf16x8*)(wt + c * 128 + ((kq * 16) ^ ((c & 7) << 4))) = bv;
        }
    }

    for (int tile = blockIdx.x; tile < ntiles; tile += gridDim.x) {
        const int base = tile * 128;
        __syncthreads();
        {
            int r = tid >> 2, q = tid & 3;
            int n = base + r;
            float v[16];
#pragma unroll
            for (int j = 0; j < 16; ++j) v[j] = 0.f;
            if (n < NN) {
                const float* hp = h + (size_t)64 * n + q * 16;
#pragma unroll
                for (int j = 0; j < 4; ++j) {
                    float4 t = *(const float4*)(hp + 4 * j);
                    v[4 * j] = t.x; v[4 * j + 1] = t.y;
                    v[4 * j + 2] = t.z; v[4 * j + 3] = t.w;
                }
            }
            bf16x8 b0, b1;
#pragma unroll
            for (int j = 0; j < 8; ++j) {
                b0[j] = (short)bf16_rne(v[j]);
                b1[j] = (short)bf16_rne(v[8 + j]);
            }
            int swr = (r & 7) << 4;
            *(bf16x8*)(hb + r * 128 + ((q * 32) ^ swr))      = b0;
            *(bf16x8*)(hb + r * 128 + ((q * 32 + 16) ^ swr)) = b1;
        }
        __syncthreads();
        f32x4 acc[2][4];
#pragma unroll
        for (int m = 0; m < 2; ++m)
#pragma unroll
            for (int n = 0; n < 4; ++n) acc[m][n] = (f32x4){0.f, 0.f, 0.f, 0.f};
#pragma unroll
        for (int ks = 0; ks < 2; ++ks) {
            int kb = ks * 64 + l4 * 16;
            bf16x8 af[2], bf[4];
#pragma unroll
            for (int m = 0; m < 2; ++m)
                af[m] = *(const bf16x8*)(hb + (32 * mi + 16 * m + l15) * 128 + (kb ^ sw));
#pragma unroll
            for (int n = 0; n < 4; ++n)
                bf[n] = *(const bf16x8*)(wt + (64 * ni + 16 * n + l15) * 128 + (kb ^ sw));
#pragma unroll
            for (int m = 0; m < 2; ++m)
#pragma unroll
                for (int n = 0; n < 4; ++n)
                    acc[m][n] = mfma16(af[m], bf[n], acc[m][n]);
        }
        __syncthreads();
        if (ni == 0) {
#pragma unroll
            for (int m = 0; m < 2; ++m)
#pragma unroll
                for (int n = 0; n < 4; ++n)
#pragma unroll
                    for (int r = 0; r < 4; ++r)
                        tp[(32 * mi + 16 * m + l4 * 4 + r) * 68 + 16 * n + l15] =
                            acc[m][n][r];
        }
        __syncthreads();
        {
            int r = tid >> 2, q = tid & 3;
            int n = base + r;
            if (n < NN) {
                float* op = Pt + (size_t)64 * n + q * 16;
#pragma unroll
                for (int j = 0; j < 4; ++j)
                    *(float4*)(op + 4 * j) = *(const float4*)&tp[r * 68 + q * 16 + 4 * j];
            }
        }
        __syncthreads();
        if (ni == 1) {
#pragma unroll
            for (int m = 0; m < 2; ++m)
#pragma unroll
                for (int n = 0; n < 4; ++n)
#pragma unroll
                    for (int r = 0; r < 4; ++r)
                        tp[(32 * mi + 16 * m + l4 * 4 + r) * 68 + 16 * n + l15] =
                            acc[m][n][r];
        }
        __syncthreads();
        {
            int r = tid >> 2, q = tid & 3;
            int n = base + r;
            if (n < NN) {
                unsigned uu[8];
#pragma unroll
                for (int j = 0; j < 8; ++j) {
                    float lo = tp[r * 68 + q * 16 + 2 * j];
                    float hi = tp[r * 68 + q * 16 + 2 * j + 1];
                    uu[j] = ((unsigned)bf16_rne(hi) << 16) | bf16_rne(lo);
                }
                uint4* op = (uint4*)(Pbu + (size_t)64 * n + q * 16);
                op[0] = make_uint4(uu[0], uu[1], uu[2], uu[3]);
                op[1] = make_uint4(uu[4], uu[5], uu[6], uu[7]);
            }
        }
    }
}

// ===========================================================================
// Edge kernel — round-14/17 structure; packed int2 IDX. UNCHANGED.
// ===========================================================================
__global__ __launch_bounds__(512, 6) void edge_kernel(
    const float* __restrict__ Pt, const unsigned short* __restrict__ Pbu,
    const int2* __restrict__ epair,
    const float* __restrict__ b1g,
    const float* __restrict__ w2g, const float* __restrict__ b2g,
    unsigned short* __restrict__ m2g, int ntiles)
{
    extern __shared__ __align__(16) char smem[];
    char*  wt2s = smem;                       // [64c][128B] swz   8192
    char*  m1s  = wt2s + 8192;                // [128r][128B] swz 16384
    float* b1s  = (float*)(m1s + 16384);      // 64 f32
    float* b2s  = b1s + 64;                   // 64 f32

    const int tid = threadIdx.x;
    const int l   = tid & 63;
    const int w   = tid >> 6;
    const int mi  = w >> 1;
    const int ni  = w & 1;
    const int l15 = l & 15;
    const int l4  = l >> 4;
    const int g7  = tid & 7;

    {
        int c = tid >> 3, kc = tid & 7;
        const float* wp = w2g + (kc * 8) * 64 + c;
        bf16x8 bv;
#pragma unroll
        for (int j = 0; j < 8; ++j) bv[j] = (short)bf16_rne(wp[j * 64]);
        *(bf16x8*)(wt2s + c * 128 + ((kc * 16) ^ ((c & 7) << 4))) = bv;
    }
    if (tid < 64) { b1s[tid] = b1g[tid]; b2s[tid] = b2g[tid]; }

    int    ix_d[2], ix_s[2];
    float4 pf_a0[2], pf_a1[2];
    uint4  pf_pb[2];

    auto IDX = [&](int tt) {
        int eb = tt * 128;
#pragma unroll
        for (int it = 0; it < 2; ++it) {
            int e = (it * 512 + tid) >> 3;
            int2 p = epair[eb + e];
            ix_s[it] = p.x;
            ix_d[it] = p.y;
        }
    };
    auto DATA = [&]() {
#pragma unroll
        for (int it = 0; it < 2; ++it) {
            const float* pt = Pt + (size_t)64 * ix_d[it] + 8 * g7;
            pf_a0[it] = *(const float4*)pt;
            pf_a1[it] = *(const float4*)(pt + 4);
            pf_pb[it] = *(const uint4*)(Pbu + (size_t)64 * ix_s[it] + 8 * g7);
        }
    };

    int tile = blockIdx.x;
    if (tile < ntiles) { IDX(tile); DATA(); }
    if (tile + gridDim.x < ntiles) IDX(tile + gridDim.x);
    barrier_lgkm();

    for (; tile < ntiles; tile += gridDim.x) {
#pragma unroll
        for (int it = 0; it < 2; ++it) {
            int e = (it * 512 + tid) >> 3;
            float4 b0  = *(const float4*)(b1s + 8 * g7);
            float4 b1v = *(const float4*)(b1s + 8 * g7 + 4);
            float v0 = silu_f(pf_a0[it].x + bflo(pf_pb[it].x) + b0.x);
            float v1 = silu_f(pf_a0[it].y + bfhi(pf_pb[it].x) + b0.y);
            float v2 = silu_f(pf_a0[it].z + bflo(pf_pb[it].y) + b0.z);
            float v3 = silu_f(pf_a0[it].w + bfhi(pf_pb[it].y) + b0.w);
            float v4 = silu_f(pf_a1[it].x + bflo(pf_pb[it].z) + b1v.x);
            float v5 = silu_f(pf_a1[it].y + bfhi(pf_pb[it].z) + b1v.y);
            float v6 = silu_f(pf_a1[it].z + bflo(pf_pb[it].w) + b1v.z);
            float v7 = silu_f(pf_a1[it].w + bfhi(pf_pb[it].w) + b1v.w);
            uint4 o;
            o.x = ((unsigned)bf16_rne(v1) << 16) | bf16_rne(v0);
            o.y = ((unsigned)bf16_rne(v3) << 16) | bf16_rne(v2);
            o.z = ((unsigned)bf16_rne(v5) << 16) | bf16_rne(v4);
            o.w = ((unsigned)bf16_rne(v7) << 16) | bf16_rne(v6);
            *(uint4*)(m1s + e * 128 + ((g7 * 16) ^ ((e & 7) << 4))) = o;
        }
        barrier_lgkm();                           // B1: m1s ready
        int nxt = tile + gridDim.x;
        if (nxt < ntiles) {
            DATA();
            if (nxt + gridDim.x < ntiles) IDX(nxt + gridDim.x);
        }
        f32x4 acc2[2][2];
#pragma unroll
        for (int m = 0; m < 2; ++m)
#pragma unroll
            for (int n = 0; n < 2; ++n) {
                float b = b2s[32 * ni + 16 * n + l15];
                acc2[m][n] = (f32x4){b, b, b, b};
            }
        const int sw = (l15 & 7) << 4;
#pragma unroll
        for (int ks = 0; ks < 2; ++ks) {
            int kb = ks * 64 + l4 * 16;
            bf16x8 af[2], bfr[2];
#pragma unroll
            for (int m = 0; m < 2; ++m)
                af[m] = *(const bf16x8*)(m1s + (32 * mi + 16 * m + l15) * 128 + (kb ^ sw));
#pragma unroll
            for (int n = 0; n < 2; ++n)
                bfr[n] = *(const bf16x8*)(wt2s + (32 * ni + 16 * n + l15) * 128 + (kb ^ sw));
#pragma unroll
            for (int m = 0; m < 2; ++m)
#pragma unroll
                for (int n = 0; n < 2; ++n)
                    acc2[m][n] = mfma16(af[m], bfr[n], acc2[m][n]);
        }
        unsigned short* mg = m2g + (size_t)(tile * 128) * 64;
#pragma unroll
        for (int m = 0; m < 2; ++m)
#pragma unroll
            for (int n = 0; n < 2; ++n)
#pragma unroll
                for (int r = 0; r < 4; ++r) {
                    int row = 32 * mi + 16 * m + l4 * 4 + r;
                    int col = 32 * ni + 16 * n + l15;
                    mg[row * 64 + col] = bf16_rne(silu_f(acc2[m][n][r]));
                }
        barrier_lgkm();                           // B2
    }
}

// ===========================================================================
// agg_kernel — round-22 proven uint2 variant (uint4 widening measured neutral).
// ===========================================================================
__global__ __launch_bounds__(256) void agg_kernel(
    const unsigned short* __restrict__ m2g, const int* __restrict__ rowptr,
    float* __restrict__ agg)
{
    int idx = blockIdx.x * 256 + threadIdx.x;
    if (idx >= NN * 16) return;
    int n = idx >> 4, c = idx & 15;
    int e0 = rowptr[n], e1 = rowptr[n + 1];
    float a0 = 0.f, a1 = 0.f, a2 = 0.f, a3 = 0.f;
    int e = e0;
    for (; e + 4 <= e1; e += 4) {
        uint2 u0 = *(const uint2*)(m2g + (size_t)(e + 0) * 64 + 4 * c);
        uint2 u1 = *(const uint2*)(m2g + (size_t)(e + 1) * 64 + 4 * c);
        uint2 u2 = *(const uint2*)(m2g + (size_t)(e + 2) * 64 + 4 * c);
        uint2 u3 = *(const uint2*)(m2g + (size_t)(e + 3) * 64 + 4 * c);
        a0 += (bflo(u0.x) + bflo(u1.x)) + (bflo(u2.x) + bflo(u3.x));
        a1 += (bfhi(u0.x) + bfhi(u1.x)) + (bfhi(u2.x) + bfhi(u3.x));
        a2 += (bflo(u0.y) + bflo(u1.y)) + (bflo(u2.y) + bflo(u3.y));
        a3 += (bfhi(u0.y) + bfhi(u1.y)) + (bfhi(u2.y) + bfhi(u3.y));
    }
    for (; e < e1; ++e) {
        uint2 u = *(const uint2*)(m2g + (size_t)e * 64 + 4 * c);
        a0 += bflo(u.x); a1 += bfhi(u.x);
        a2 += bflo(u.y); a3 += bfhi(u.y);
    }
    *(float4*)(agg + (size_t)64 * n + 4 * c) = make_float4(a0, a1, a2, a3);
}

// ===========================================================================
// node_mfma_kernel — round-22 proven. UNCHANGED.
// ===========================================================================
__global__ __launch_bounds__(512, 1) void node_mfma_kernel(
    const float* __restrict__ h, const float* __restrict__ agg,
    const float* __restrict__ w1g, const float* __restrict__ b1g,
    const float* __restrict__ w2g, const float* __restrict__ b2g,
    float* __restrict__ outp, int ntiles)
{
    extern __shared__ __align__(16) char smem[];
    char*  hbA = smem;                    // 16384 (k 0-63 = h)
    char*  hbB = hbA + 16384;             // 16384 (k 64-127 = agg)
    char*  wtA = hbB + 16384;             //  8192 (W1 k 0-63)
    char*  wtB = wtA + 8192;              //  8192 (W1 k 64-127)
    char*  wt2 = wtB + 8192;              //  8192 (W2)
    char*  m1s = wt2 + 8192;              // 16384 (bf16 m1)
    float* tp  = (float*)(m1s + 16384);   // 34816
    float* b1s = (float*)((char*)tp + 34816);  // 64
    float* b2s = b1s + 64;                     // 64

    const int tid = threadIdx.x;
    const int l   = tid & 63;
    const int w   = tid >> 6;
    const int mi  = w >> 1;
    const int ni  = w & 1;
    const int l15 = l & 15;
    const int l4  = l >> 4;
    const int sw  = (l15 & 7) << 4;

    {
        int c = tid >> 3, kc = tid & 7;
        const float* wpA = w1g + (kc * 8) * 64 + c;
        const float* wpB = w1g + (64 + kc * 8) * 64 + c;
        const float* wp2 = w2g + (kc * 8) * 64 + c;
        bf16x8 bA, bB, b2v;
#pragma unroll
        for (int j = 0; j < 8; ++j) {
            bA[j]  = (short)bf16_rne(wpA[j * 64]);
            bB[j]  = (short)bf16_rne(wpB[j * 64]);
            b2v[j] = (short)bf16_rne(wp2[j * 64]);
        }
        int off = c * 128 + ((kc * 16) ^ ((c & 7) << 4));
        *(bf16x8*)(wtA + off) = bA;
        *(bf16x8*)(wtB + off) = bB;
        *(bf16x8*)(wt2 + off) = b2v;
    }
    if (tid < 64) { b1s[tid] = b1g[tid]; b2s[tid] = b2g[tid]; }

    for (int tile = blockIdx.x; tile < ntiles; tile += gridDim.x) {
        const int base = tile * 128;
        __syncthreads();
        {
            int r = tid >> 2, q = tid & 3;
            int n = base + r;
            int swr = (r & 7) << 4;
#pragma unroll
            for (int srcsel = 0; srcsel < 2; ++srcsel) {
                const float* src = srcsel ? agg : h;
                char* dst = srcsel ? hbB : hbA;
                float v[16];
#pragma unroll
                for (int j = 0; j < 16; ++j) v[j] = 0.f;
                if (n < NN) {
                    const float* hp = src + (size_t)64 * n + q * 16;
#pragma unroll
                    for (int j = 0; j < 4; ++j) {
                        float4 t = *(const float4*)(hp + 4 * j);
                        v[4 * j] = t.x; v[4 * j + 1] = t.y;
                        v[4 * j + 2] = t.z; v[4 * j + 3] = t.w;
                    }
                }
                bf16x8 c0, c1;
#pragma unroll
                for (int j = 0; j < 8; ++j) {
                    c0[j] = (short)bf16_rne(v[j]);
                    c1[j] = (short)bf16_rne(v[8 + j]);
                }
                *(bf16x8*)(dst + r * 128 + ((q * 32) ^ swr))      = c0;
                *(bf16x8*)(dst + r * 128 + ((q * 32 + 16) ^ swr)) = c1;
            }
        }
        __syncthreads();
        f32x4 acc[2][2];
#pragma unroll
        for (int m = 0; m < 2; ++m)
#pragma unroll
            for (int n = 0; n < 2; ++n) {
                float b = b1s[32 * ni + 16 * n + l15];
                acc[m][n] = (f32x4){b, b, b, b};
            }
#pragma unroll
        for (int half = 0; half < 2; ++half) {
            const char* hb = half ? hbB : hbA;
            const char* wt = half ? wtB : wtA;
#pragma unroll
            for (int ks = 0; ks < 2; ++ks) {
                int kb = ks * 64 + l4 * 16;
                bf16x8 af[2], bf[2];
#pragma unroll
                for (int m = 0; m < 2; ++m)
                    af[m] = *(const bf16x8*)(hb + (32 * mi + 16 * m + l15) * 128 + (kb ^ sw));
#pragma unroll
                for (int n = 0; n < 2; ++n)
                    bf[n] = *(const bf16x8*)(wt + (32 * ni + 16 * n + l15) * 128 + (kb ^ sw));
#pragma unroll
                for (int m = 0; m < 2; ++m)
#pragma unroll
                    for (int n = 0; n < 2; ++n)
                        acc[m][n] = mfma16(af[m], bf[n], acc[m][n]);
            }
        }
#pragma unroll
        for (int m = 0; m < 2; ++m)
#pragma unroll
            for (int n = 0; n < 2; ++n)
#pragma unroll
                for (int r = 0; r < 4; ++r) {
                    int row = 32 * mi + 16 * m + l4 * 4 + r;
                    int col = 32 * ni + 16 * n + l15;
                    *(unsigned short*)(m1s + row * 128 + ((col * 2) ^ ((row & 7) << 4))) =
                        bf16_rne(silu_f(acc[m][n][r]));
                }
        __syncthreads();
        f32x4 acc2[2][2];
#pragma unroll
        for (int m = 0; m < 2; ++m)
#pragma unroll
            for (int n = 0; n < 2; ++n) {
                float b = b2s[32 * ni + 16 * n + l15];
                acc2[m][n] = (f32x4){b, b, b, b};
            }
#pragma unroll
        for (int ks = 0; ks < 2; ++ks) {
            int kb = ks * 64 + l4 * 16;
            bf16x8 af[2], bfr[2];
#pragma unroll
            for (int m = 0; m < 2; ++m)
                af[m] = *(const bf16x8*)(m1s + (32 * mi + 16 * m + l15) * 128 + (kb ^ sw));
#pragma unroll
            for (int n = 0; n < 2; ++n)
                bfr[n] = *(const bf16x8*)(wt2 + (32 * ni + 16 * n + l15) * 128 + (kb ^ sw));
#pragma unroll
            for (int m = 0; m < 2; ++m)
#pragma unroll
                for (int n = 0; n < 2; ++n)
                    acc2[m][n] = mfma16(af[m], bfr[n], acc2[m][n]);
        }
#pragma unroll
        for (int m = 0; m < 2; ++m)
#pragma unroll
            for (int n = 0; n < 2; ++n)
#pragma unroll
                for (int r = 0; r < 4; ++r)
                    tp[(32 * mi + 16 * m + l4 * 4 + r) * 68 + 32 * ni + 16 * n + l15] =
                        acc2[m][n][r];
        __syncthreads();
        {
            int r = tid >> 2, q = tid & 3;
            int n = base + r;
            if (n < NN) {
                const float* hp = h + (size_t)64 * n + q * 16;
                float* op = outp + (size_t)64 * n + q * 16;
#pragma unroll
                for (int j = 0; j < 4; ++j) {
                    float4 hv = *(const float4*)(hp + 4 * j);
                    const float* tv = &tp[r * 68 + q * 16 + 4 * j];
                    *(float4*)(op + 4 * j) = make_float4(
                        tv[0] + hv.x, tv[1] + hv.y, tv[2] + hv.z, tv[3] + hv.w);
                }
            }
        }
    }
}

// ===========================================================================
// Readout row-MLP (K1=64, segmented scatter into gsum) — unchanged.
// ===========================================================================
__global__ __launch_bounds__(512, 1) void rowmlp_ro_kernel(
    const float* __restrict__ A,
    const float* __restrict__ w1g, const float* __restrict__ b1g,
    const float* __restrict__ w2g, const float* __restrict__ b2g,
    const int* __restrict__ seg, float* __restrict__ outp,
    int nrows, int ntiles)
{
    extern __shared__ float lds[];
    float* ws1  = lds;
    float* ws2  = ws1 + 4096;
    float* wb1  = ws2 + 4096;
    float* wb2  = wb1 + 64;
    float* cats = wb2 + 64;
    float* m1s  = cats + 128 * 68;
    int*   segs = (int*)(m1s + 128 * 68);

    const int tid = threadIdx.x;
    const int tr  = tid & 31;
    const int tc  = tid >> 5;

    for (int i = tid; i < 1024; i += 512) {
        *(float4*)&ws1[4 * i] = *(const float4*)&w1g[4 * i];
        *(float4*)&ws2[4 * i] = *(const float4*)&w2g[4 * i];
    }
    if (tid < 64) { wb1[tid] = b1g[tid]; wb2[tid] = b2g[tid]; }

    for (int tile = blockIdx.x; tile < ntiles; tile += gridDim.x) {
        const int base = tile * 128;
        __syncthreads();
        if (tid < 128) segs[tid] = (base + tid < nrows) ? seg[base + tid] : -1;
#pragma unroll
        for (int rep = 0; rep < 4; ++rep) {
            int idx = rep * 512 + tid;
            int r = idx >> 4, q = idx & 15;
            int n = base + r;
            float4 v = make_float4(0.f, 0.f, 0.f, 0.f);
            if (n < nrows) v = *(const float4*)(A + 64 * n + 4 * q);
            *(float4*)&cats[r * 68 + 4 * q] = v;
        }
        __syncthreads();
        float acc[4][4];
#pragma unroll
        for (int jj = 0; jj < 4; ++jj)
#pragma unroll
            for (int ii = 0; ii < 4; ++ii) acc[jj][ii] = wb1[4 * tc + ii];
#pragma unroll 4
        for (int k16 = 0; k16 < 16; ++k16) {
            float4 bv0 = *(const float4*)&ws1[(4 * k16 + 0) * 64 + 4 * tc];
            float4 bv1 = *(const float4*)&ws1[(4 * k16 + 1) * 64 + 4 * tc];
            float4 bv2 = *(const float4*)&ws1[(4 * k16 + 2) * 64 + 4 * tc];
            float4 bv3 = *(const float4*)&ws1[(4 * k16 + 3) * 64 + 4 * tc];
#pragma unroll
            for (int jj = 0; jj < 4; ++jj) {
                float4 av = *(const float4*)&cats[(tr + 32 * jj) * 68 + 4 * k16];
                acc[jj][0] = fmaf(av.x, bv0.x, fmaf(av.y, bv1.x, fmaf(av.z, bv2.x, fmaf(av.w, bv3.x, acc[jj][0]))));
                acc[jj][1] = fmaf(av.x, bv0.y, fmaf(av.y, bv1.y, fmaf(av.z, bv2.y, fmaf(av.w, bv3.y, acc[jj][1]))));
                acc[jj][2] = fmaf(av.x, bv0.z, fmaf(av.y, bv1.z, fmaf(av.z, bv2.z, fmaf(av.w, bv3.z, acc[jj][2]))));
                acc[jj][3] = fmaf(av.x, bv0.w, fmaf(av.y, bv1.w, fmaf(av.z, bv2.w, fmaf(av.w, bv3.w, acc[jj][3]))));
            }
        }
#pragma unroll
        for (int jj = 0; jj < 4; ++jj) {
            float4 v;
            v.x = silu_f(acc[jj][0]); v.y = silu_f(acc[jj][1]);
            v.z = silu_f(acc[jj][2]); v.w = silu_f(acc[jj][3]);
            *(float4*)&m1s[(tr + 32 * jj) * 68 + 4 * tc] = v;
        }
        __syncthreads();
        float acc2[4][4];
#pragma unroll
        for (int jj = 0; jj < 4; ++jj)
#pragma unroll
            for (int ii = 0; ii < 4; ++ii) acc2[jj][ii] = wb2[4 * tc + ii];
#pragma unroll 4
        for (int k16 = 0; k16 < 16; ++k16) {
            float4 bv0 = *(const float4*)&ws2[(4 * k16 + 0) * 64 + 4 * tc];
            float4 bv1 = *(const float4*)&ws2[(4 * k16 + 1) * 64 + 4 * tc];
            float4 bv2 = *(const float4*)&ws2[(4 * k16 + 2) * 64 + 4 * tc];
            float4 bv3 = *(const float4*)&ws2[(4 * k16 + 3) * 64 + 4 * tc];
#pragma unroll
            for (int jj = 0; jj < 4; ++jj) {
                float4 av = *(const float4*)&m1s[(tr + 32 * jj) * 68 + 4 * k16];
                acc2[jj][0] = fmaf(av.x, bv0.x, fmaf(av.y, bv1.x, fmaf(av.z, bv2.x, fmaf(av.w, bv3.x, acc2[jj][0]))));
                acc2[jj][1] = fmaf(av.x, bv0.y, fmaf(av.y, bv1.y, fmaf(av.z, bv2.y, fmaf(av.w, bv3.y, acc2[jj][1]))));
                acc2[jj][2] = fmaf(av.x, bv0.z, fmaf(av.y, bv1.z, fmaf(av.z, bv2.z, fmaf(av.w, bv3.z, acc2[jj][2]))));
                acc2[jj][3] = fmaf(av.x, bv0.w, fmaf(av.y, bv1.w, fmaf(av.z, bv2.w, fmaf(av.w, bv3.w, acc2[jj][3]))));
            }
        }
#pragma unroll
        for (int jj = 0; jj < 4; ++jj) {
            int r = tr + 32 * jj;
            int n = base + r;
            int gid = segs[r];
            float4 vv = (n < nrows) ? make_float4(acc2[jj][0], acc2[jj][1], acc2[jj][2], acc2[jj][3])
                                    : make_float4(0.f, 0.f, 0.f, 0.f);
            unsigned f = (tr == 0 || segs[(r > 0) ? r - 1 : 0] != gid) ? 1u : 0u;
#pragma unroll
            for (int s = 1; s < 32; s <<= 1) {
                float ux = __shfl_up(vv.x, s, 32);
                float uy = __shfl_up(vv.y, s, 32);
                float uz = __shfl_up(vv.z, s, 32);
                float uw = __shfl_up(vv.w, s, 32);
                unsigned uf = __shfl_up(f, s, 32);
                if (tr >= s) {
                    if (!f) { vv.x += ux; vv.y += uy; vv.z += uz; vv.w += uw; }
                    f |= uf;
                }
            }
            bool tail = (tr == 31) || (segs[r + 1] != gid);
            if (tail && gid >= 0) {
                float* bp = outp + 64 * gid + 4 * tc;
                atomicAdd(bp + 0, vv.x); atomicAdd(bp + 1, vv.y);
                atomicAdd(bp + 2, vv.z); atomicAdd(bp + 3, vv.w);
            }
        }
    }
}

__global__ __launch_bounds__(256) void proj_kernel(
    const float* __restrict__ x, const float* __restrict__ w,
    const float* __restrict__ b, float* __restrict__ h, int n)
{
    int i = blockIdx.x * 256 + threadIdx.x;
    if (i >= n * 64) return;
    int node = i >> 6, j = i & 63;
    const float* xr = x + node * 14;
    float acc = b[j];
#pragma unroll
    for (int k = 0; k < 14; ++k) acc = fmaf(xr[k], w[k * 64 + j], acc);
    h[i] = acc;
}

__global__ __launch_bounds__(256) void head_kernel(
    const float* __restrict__ gsum,
    const float* __restrict__ w3, const float* __restrict__ b3,
    const float* __restrict__ w4, const float* __restrict__ b4,
    float* __restrict__ out, int g_count)
{
    int wid  = (blockIdx.x * 256 + threadIdx.x) >> 6;
    int lane = threadIdx.x & 63;
    if (wid >= g_count) return;
    float v = gsum[wid * 64 + lane];
    float t = b3[lane];
#pragma unroll
    for (int k = 0; k < 64; ++k) {
        float a = __shfl(v, k, 64);
        t = fmaf(a, w3[k * 64 + lane], t);
    }
    t = silu_f(t);
    float r = t * w4[lane];
#pragma unroll
    for (int off = 32; off; off >>= 1) r += __shfl_down(r, off, 64);
    if (lane == 0) out[wid] = r + b4[0];
}

extern "C" void kernel_launch(void* const* d_in, const int* in_sizes, int n_in,
                              void* d_out, int out_size, void* d_ws, size_t ws_size,
                              hipStream_t stream)
{
    const float* x      = (const float*)d_in[0];
    const int*   ei     = (const int*)d_in[2];
    const int*   batch  = (const int*)d_in[3];
    const float* proj_w = (const float*)d_in[4];
    const float* proj_b = (const float*)d_in[5];
    const float* ew1 = (const float*)d_in[6];
    const float* eb1 = (const float*)d_in[7];
    const float* ew2 = (const float*)d_in[8];
    const float* eb2 = (const float*)d_in[9];
    const float* nw1 = (const float*)d_in[10];
    const float* nb1 = (const float*)d_in[11];
    const float* nw2 = (const float*)d_in[12];
    const float* nb2 = (const float*)d_in[13];
    const float* l1w = (const float*)d_in[14]; const float* l1b = (const float*)d_in[15];
    const float* l2w = (const float*)d_in[16]; const float* l2b = (const float*)d_in[17];
    const float* l3w = (const float*)d_in[18]; const float* l3b = (const float*)d_in[19];
    const float* l4w = (const float*)d_in[20]; const float* l4b = (const float*)d_in[21];

    float* out  = (float*)d_out;
    float* h    = out + GG;                      // per_atom_out doubles as h

    unsigned short* m2g = (unsigned short*)d_ws;             // [E,64] bf16 = 102.4MB
    float* gsum = (float*)(m2g + (size_t)EE * 64);           // [G,64]
    float* Pt   = gsum + (size_t)GG * 64;                    // [N,64] f32
    unsigned short* Pbu = (unsigned short*)(Pt + (size_t)NN * 64);  // [N,64] bf16
    int* deg8    = (int*)(Pbu + (size_t)NN * 64);            // [8][N]
    int* rowptr  = deg8 + 8 * NN;                            // N+1
    int* cursor8 = rowptr + NN + 1;                          // [8][N]
    int2* epair  = (int2*)(((uintptr_t)(cursor8 + 8 * NN) + 15) & ~(uintptr_t)15);  // [E]
    int* bsum    = (int*)(epair + EE);                       // [98]
    float* agg   = Pt;  // alias: Pt dead after edge_kernel, rebuilt next layer

    const size_t edge_lds = 8192 + 16384 + 256 + 256;                 // 25088
    const size_t pk_lds   = 16384 + 16384 + 34816;                    // 67584
    const size_t node_lds = 16384 * 3 + 8192 * 3 + 34816 + 512;       // 109056
    const size_t ro_lds   = (size_t)(4096 + 4096 + 128 + 128 * 68 + 128 * 68) * 4 + 128 * 4;

    (void)hipFuncSetAttribute((const void*)edge_kernel,
                              hipFuncAttributeMaxDynamicSharedMemorySize, (int)edge_lds);
    (void)hipFuncSetAttribute((const void*)pk_kernel,
                              hipFuncAttributeMaxDynamicSharedMemorySize, (int)pk_lds);
    (void)hipFuncSetAttribute((const void*)node_mfma_kernel,
                              hipFuncAttributeMaxDynamicSharedMemorySize, (int)node_lds);
    (void)hipFuncSetAttribute((const void*)rowmlp_ro_kernel,
                              hipFuncAttributeMaxDynamicSharedMemorySize, (int)ro_lds);

    // --- CSR build (8-way sharded, dst-sorted packed edge list) ---
    const int nb = (NN + 511) / 512;           // 98
    hipMemsetAsync(deg8, 0, (size_t)8 * NN * sizeof(int), stream);
    hipMemsetAsync(gsum, 0, (size_t)GG * 64 * sizeof(float), stream);
    hist_kernel<<<(EE + 255) / 256, 256, 0, stream>>>(ei, deg8);
    scanA_kernel<<<nb, 512, 0, stream>>>(deg8, rowptr, bsum);
    scanB_kernel<<<1, 128, 0, stream>>>(bsum, nb);
    scanC_kernel<<<nb, 512, 0, stream>>>(rowptr, cursor8, deg8, bsum);
    scatter_kernel<<<(EE + 255) / 256, 256, 0, stream>>>(ei, cursor8, epair);

    proj_kernel<<<(NN * 64 + 255) / 256, 256, 0, stream>>>(x, proj_w, proj_b, h, NN);

    const int etiles = EE / 128;               // 6250 (exact)
    const int ntiles = (NN + 127) / 128;       // 391
    for (int l = 0; l < LL; ++l) {
        pk_kernel<<<ntiles, 512, pk_lds, stream>>>(h, ew1 + l * 8192, Pt, Pbu, ntiles);
        edge_kernel<<<1024, 512, edge_lds, stream>>>(
            Pt, Pbu, epair, eb1 + l * 64, ew2 + l * 4096, eb2 + l * 64,
            m2g, etiles);
        agg_kernel<<<(NN * 16 + 255) / 256, 256, 0, stream>>>(m2g, rowptr, agg);
        node_mfma_kernel<<<196, 512, node_lds, stream>>>(
            h, agg, nw1 + l * 8192, nb1 + l * 64, nw2 + l * 4096, nb2 + l * 64,
            h, ntiles);
    }
    rowmlp_ro_kernel<<<196, 512, ro_lds, stream>>>(
        h, l1w, l1b, l2w, l2b, batch, gsum, NN, ntiles);
    head_kernel<<<GG / 4, 256, 0, stream>>>(gsum, l3w, l3b, l4w, l4b, out, GG);
}